// Round 7
// baseline (992.656 us; speedup 1.0000x reference)
//
#include <hip/hip_runtime.h>
#include <math.h>

// Problem constants (fixed by the reference)
#define NP    100000      // primal nodes
#define EP    1600000     // primal edges
#define NDU   1600000     // dual nodes
#define EDU   3200000     // dual edges
#define FIN   512
#define NHEAD 8
#define HIDC  8
#define NCLS  16
#define NEGS  0.2f
#define TPB   256

static __device__ __forceinline__ float lrelu(float x){ return x > 0.f ? x : NEGS*x; }

// ===================== CSR build (per-dst), bucketed, atomic-free =====================
// R1: flat fill = random-line transaction bound. R3: global atomics don't
// benefit from L2 windows (cross-XCD coherence point). R4 design: bscat makes
// bucket b's edges contiguous in pairs[]; k_csr builds deg/offs/col/dinv per
// bucket with LDS atomics + LDS scan only.

#define BKT_MAX 256   // >= bucket count (196)
#define BCHUNK  2048  // edges per block in bucket kernels (8/thread)

__global__ void k_bhist(const int* __restrict__ dst, int* __restrict__ bcnt,
                        int n, int shift){
  __shared__ int cnt[BKT_MAX];
  for(int i=threadIdx.x;i<BKT_MAX;i+=TPB) cnt[i]=0;
  __syncthreads();
  int base = blockIdx.x*BCHUNK;
  #pragma unroll
  for(int i=0;i<8;i++){
    int e = base + i*TPB + threadIdx.x;
    if(e<n) atomicAdd(&cnt[dst[e]>>shift],1);
  }
  __syncthreads();
  for(int i=threadIdx.x;i<BKT_MAX;i+=TPB) if(cnt[i]) atomicAdd(bcnt+i, cnt[i]);
}

__global__ void k_bscan(int* __restrict__ bcnt, int nb){
  __shared__ int lds[BKT_MAX];
  for(int i=threadIdx.x;i<nb;i+=TPB) lds[i]=bcnt[i];
  __syncthreads();
  if(threadIdx.x==0){ int s=0; for(int i=0;i<nb;i++){ int v=lds[i]; lds[i]=s; s+=v; } }
  __syncthreads();
  for(int i=threadIdx.x;i<nb;i+=TPB) bcnt[i]=lds[i];
}

// block-local counting scatter: edges -> bucketed (src,dst) pairs.
// After this kernel, btail[b] = END of bucket b's region.
__global__ __launch_bounds__(TPB) void k_bscat(const int* __restrict__ src,
                                               const int* __restrict__ dst,
                                               int* __restrict__ btail,
                                               int2* __restrict__ pairs,
                                               int n, int shift){
  __shared__ int cnt[BKT_MAX];
  __shared__ int bbase[BKT_MAX];
  for(int i=threadIdx.x;i<BKT_MAX;i+=TPB) cnt[i]=0;
  __syncthreads();
  int base = blockIdx.x*BCHUNK;
  int sv[8], dv[8], rv[8];
  #pragma unroll
  for(int i=0;i<8;i++){
    int e = base + i*TPB + threadIdx.x;
    if(e<n){ sv[i]=src[e]; dv[i]=dst[e]; rv[i]=atomicAdd(&cnt[dv[i]>>shift],1); }
    else rv[i]=-1;
  }
  __syncthreads();
  for(int i=threadIdx.x;i<BKT_MAX;i+=TPB){
    int c = cnt[i];
    bbase[i] = c ? atomicAdd(btail+i, c) : 0;
  }
  __syncthreads();
  #pragma unroll
  for(int i=0;i<8;i++){
    if(rv[i]>=0){
      int b = dv[i]>>shift;
      pairs[bbase[b]+rv[i]] = make_int2(sv[i], dv[i]);
    }
  }
}

// one WG per bucket: LDS hist -> LDS scan -> offs/dinv writeback -> LDS-ranked
// col scatter. Dynamic LDS: (1<<shift) ints.
__global__ __launch_bounds__(TPB) void k_csr(const int2* __restrict__ pairs,
                                             const int* __restrict__ btail,
                                             int* __restrict__ offs,
                                             float* __restrict__ dinv,
                                             int* __restrict__ col,
                                             int nnodes, int shift){
  extern __shared__ int ldeg[];
  __shared__ int ttmp[TPB];
  const int b    = blockIdx.x;
  const int tid  = threadIdx.x;
  const int ebeg = b ? btail[b-1] : 0;
  const int eend = btail[b];
  const int node0 = b << shift;
  const int W     = 1 << shift;
  const int PW    = W / TPB;

  for(int i=tid;i<W;i+=TPB) ldeg[i]=0;
  __syncthreads();
  for(int e=ebeg+tid; e<eend; e+=TPB)
    atomicAdd(&ldeg[pairs[e].y - node0], 1);
  __syncthreads();

  const int base = tid*PW;
  int s = 0;
  for(int i=0;i<PW;i++) s += ldeg[base+i];
  ttmp[tid] = s; __syncthreads();
  for(int off=1; off<TPB; off<<=1){
    int t = (tid>=off)? ttmp[tid-off] : 0;
    __syncthreads(); ttmp[tid] += t; __syncthreads();
  }
  int run = ttmp[tid] - s;

  for(int i=0;i<PW;i++){
    int d  = base + i;
    int g  = node0 + d;
    int dg = ldeg[d];
    if(g < nnodes){
      offs[g] = ebeg + run + dg;                  // inclusive
      dinv[g] = rsqrtf((float)dg + 1.0f);
    }
    ldeg[d] = ebeg + run;                         // exclusive start (global col idx)
    run += dg;
  }
  __syncthreads();

  for(int e=ebeg+tid; e<eend; e+=TPB){
    int2 p = pairs[e];
    int pos = atomicAdd(&ldeg[p.y - node0], 1);
    col[pos] = p.x;
  }
}

// ===================== dual (line-graph) GCN branch =====================
// R2: GCN is linear -> factor W out of the gather. PX = dinv*dx prescaled;
// gathers are pure channel sums; dense W-apply once per node in-register.

__global__ void k_pscale(const float* __restrict__ dx, const float* __restrict__ dinv,
                         float4* __restrict__ PX){
  int n = blockIdx.x*TPB + threadIdx.x;
  if(n >= NDU) return;
  float4 v = *(const float4*)(dx + (size_t)n*4);
  float s = dinv[n];
  PX[n] = make_float4(v.x*s, v.y*s, v.z*s, v.w*s);
}

// layer 1: 4 lanes per node (channel-parallel gather), fused W-apply.
__global__ __launch_bounds__(TPB) void k_dual1(const float* __restrict__ PX,
                                               const float* __restrict__ Wg1,
                                               const float* __restrict__ bg1,
                                               const float* __restrict__ dinv,
                                               const int* __restrict__ offs,
                                               const int* __restrict__ col,
                                               float* __restrict__ P2){
  int t = blockIdx.x*TPB + threadIdx.x;   // over NDU*4
  if(t >= NDU*4) return;
  int d = t >> 2, c = t & 3;
  int beg = d ? offs[d-1] : 0;
  int end = offs[d];
  float acc = PX[d*4 + c];                 // self loop
  for(int j=beg; j<end; j++) acc += PX[col[j]*4 + c];
  float v0 = __shfl(acc, 0, 4), v1 = __shfl(acc, 1, 4);
  float v2 = __shfl(acc, 2, 4), v3 = __shfl(acc, 3, 4);
  float di = dinv[d];
  int ch = 2*c;
  float z0 = di*(v0*Wg1[ch]   + v1*Wg1[8+ch]   + v2*Wg1[16+ch]   + v3*Wg1[24+ch])   + bg1[ch];
  float z1 = di*(v0*Wg1[ch+1] + v1*Wg1[8+ch+1] + v2*Wg1[16+ch+1] + v3*Wg1[24+ch+1]) + bg1[ch+1];
  z0 = z0 > 0.f ? z0 : 0.f;
  z1 = z1 > 0.f ? z1 : 0.f;
  *(float2*)(P2 + (size_t)d*8 + ch) = make_float2(di*z0, di*z1);
}

// layer 2: 8 lanes per node, fused W-apply -> final Qo.
__global__ __launch_bounds__(TPB) void k_dual2(const float* __restrict__ P2,
                                               const float* __restrict__ Wg2,
                                               const float* __restrict__ bg2,
                                               const float* __restrict__ dinv,
                                               const int* __restrict__ offs,
                                               const int* __restrict__ col,
                                               float* __restrict__ Qo){
  int t = blockIdx.x*TPB + threadIdx.x;   // over NDU*8
  if(t >= NDU*8) return;
  int d = t >> 3, c = t & 7;
  int beg = d ? offs[d-1] : 0;
  int end = offs[d];
  float acc = P2[d*8 + c];                 // self loop
  for(int j=beg; j<end; j++) acc += P2[col[j]*8 + c];
  float v[8];
  #pragma unroll
  for(int k=0;k<8;k++) v[k] = __shfl(acc, k, 8);
  float di = dinv[d];
  int ch = 2*c;
  float z0 = 0.f, z1 = 0.f;
  #pragma unroll
  for(int k=0;k<8;k++){
    z0 += v[k]*Wg2[k*16 + ch];
    z1 += v[k]*Wg2[k*16 + ch + 1];
  }
  *(float2*)(Qo + (size_t)d*16 + ch) = make_float2(di*z0 + bg2[ch], di*z1 + bg2[ch+1]);
}

// ===================== primal GAT branch =====================

// H = x @ W1 : [100000,512]x[512,64], fp32 register-tiled vector GEMM.
// R6 rewrite: old version was latency-bound (VALUBusy 41%, Occ 26%): grid
// 782 blocks x 4 waves = 12 waves/CU, and stage->sync->compute->sync exposed
// the x-tile HBM latency at every barrier. Now: 512 threads (24 waves/CU at
// same grid), 4x4 register tile/thread, double-buffered LDS with REGISTER
// PREFETCH (load tile k0+1 into regs before computing k0, write to the other
// LDS buffer after, ONE barrier per iteration). ws padded to 68.
#define GBM 128
#define GBK 32
#define GT  512
__global__ __launch_bounds__(GT) void k_gemm1(const float* __restrict__ x,
                                              const float* __restrict__ W,
                                              float* __restrict__ H){
  __shared__ float xs[2][GBK][GBM+4];   // 2*32*132*4 = 33.8 KB (transposed)
  __shared__ float ws[2][GBK][68];      // 2*32*68*4  = 17.4 KB
  const int tx = threadIdx.x;
  const int r0 = blockIdx.x*GBM;
  const int cg = tx & 15;               // 4-col group: cols cg*4..+3
  const int rg = tx >> 4;               // 0..31: rows rg*4..+3

  float acc[4][4];
  #pragma unroll
  for(int i=0;i<4;i++)
    #pragma unroll
    for(int j=0;j<4;j++) acc[i][j] = 0.f;

  // x staging: 128 rows x 8 float4 = 1024 chunks, 2/thread
  const int xrow = tx >> 3;             // 0..63 (+64 for q=1)
  const int xkc  = (tx & 7)*4;
  // W staging: 32 k x 16 float4 = 512 chunks, 1/thread
  const int wk = tx >> 4;               // 0..31
  const int wc = (tx & 15)*4;

  float4 xv0, xv1, wv;
  // prologue: load + write tile 0
  {
    int gr0 = r0 + xrow, gr1 = gr0 + 64;
    xv0 = (gr0<NP)? *(const float4*)(x + (size_t)gr0*FIN + xkc) : make_float4(0,0,0,0);
    xv1 = (gr1<NP)? *(const float4*)(x + (size_t)gr1*FIN + xkc) : make_float4(0,0,0,0);
    wv  = *(const float4*)(W + (size_t)wk*64 + wc);
    int r = xrow;
    xs[0][xkc+0][r]=xv0.x; xs[0][xkc+1][r]=xv0.y; xs[0][xkc+2][r]=xv0.z; xs[0][xkc+3][r]=xv0.w;
    r += 64;
    xs[0][xkc+0][r]=xv1.x; xs[0][xkc+1][r]=xv1.y; xs[0][xkc+2][r]=xv1.z; xs[0][xkc+3][r]=xv1.w;
    *(float4*)(&ws[0][wk][wc]) = wv;
  }
  __syncthreads();

  int cur = 0;
  for(int k0=0; k0<FIN; k0+=GBK){
    int nk = k0 + GBK;
    if(nk < FIN){
      // prefetch next tile into registers (latency hides under compute)
      int gr0 = r0 + xrow, gr1 = gr0 + 64;
      xv0 = (gr0<NP)? *(const float4*)(x + (size_t)gr0*FIN + nk + xkc) : make_float4(0,0,0,0);
      xv1 = (gr1<NP)? *(const float4*)(x + (size_t)gr1*FIN + nk + xkc) : make_float4(0,0,0,0);
      wv  = *(const float4*)(W + (size_t)(nk+wk)*64 + wc);
    }
    // compute on cur
    #pragma unroll 8
    for(int kk=0;kk<GBK;kk++){
      const float4 a = *(const float4*)(&xs[cur][kk][rg*4]);
      const float4 b = *(const float4*)(&ws[cur][kk][cg*4]);
      const float av[4] = {a.x,a.y,a.z,a.w};
      const float bv[4] = {b.x,b.y,b.z,b.w};
      #pragma unroll
      for(int i=0;i<4;i++)
        #pragma unroll
        for(int j=0;j<4;j++)
          acc[i][j] += av[i]*bv[j];
    }
    if(nk < FIN){
      int nxt = cur^1;
      int r = xrow;
      xs[nxt][xkc+0][r]=xv0.x; xs[nxt][xkc+1][r]=xv0.y; xs[nxt][xkc+2][r]=xv0.z; xs[nxt][xkc+3][r]=xv0.w;
      r += 64;
      xs[nxt][xkc+0][r]=xv1.x; xs[nxt][xkc+1][r]=xv1.y; xs[nxt][xkc+2][r]=xv1.z; xs[nxt][xkc+3][r]=xv1.w;
      *(float4*)(&ws[nxt][wk][wc]) = wv;
      __syncthreads();
      cur = nxt;
    }
  }
  #pragma unroll
  for(int i=0;i<4;i++){
    int gr = r0 + rg*4 + i;
    if(gr < NP)
      *(float4*)(H + (size_t)gr*64 + cg*4) =
          make_float4(acc[i][0],acc[i][1],acc[i][2],acc[i][3]);
  }
}

__global__ void k_alpha(const float* __restrict__ H, const float* __restrict__ aw_s,
                        const float* __restrict__ aw_d,
                        float* __restrict__ als, float* __restrict__ ald){
  int i = blockIdx.x*TPB + threadIdx.x;     // over NP*8
  if(i >= NP*NHEAD) return;
  int n = i >> 3, h = i & 7;
  const float* hp = H + n*64 + h*8;
  float s = 0.f, d = 0.f;
  #pragma unroll
  for(int c=0;c<8;c++){ float v = hp[c]; s += v*aw_s[h*8+c]; d += v*aw_d[h*8+c]; }
  als[i] = s; ald[i] = d;
}

// GAT layer-1 gather: one wave per dst node, SINGLE-PASS softmax (R4),
// edge loop UNROLLED x4 with independent accumulator chains (R5).
__global__ __launch_bounds__(TPB) void k_agg1(const int* __restrict__ offs,
                                              const int* __restrict__ col,
                                              const float* __restrict__ als,
                                              const float* __restrict__ ald,
                                              const float* __restrict__ H,
                                              const float* __restrict__ b1,
                                              float* __restrict__ O){
  int d = (blockIdx.x*TPB + threadIdx.x) >> 6;   // wave per dst
  int lane = threadIdx.x & 63;
  int hc = lane >> 3;                            // head for this channel
  int beg = d ? offs[d-1] : 0;
  int end = offs[d];
  float aldc = ald[d*8 + hc];
  float den0=0.f, den1=0.f, den2=0.f, den3=0.f;
  float acc0=0.f, acc1=0.f, acc2=0.f, acc3=0.f;
  int j = beg;
  for(; j+4<=end; j+=4){
    int s0=col[j], s1=col[j+1], s2=col[j+2], s3=col[j+3];
    float a0=als[s0*8+hc], a1=als[s1*8+hc], a2=als[s2*8+hc], a3=als[s3*8+hc];
    float h0=H[s0*64+lane], h1=H[s1*64+lane], h2=H[s2*64+lane], h3=H[s3*64+lane];
    float w0=__expf(lrelu(a0+aldc)); den0+=w0; acc0+=w0*h0;
    float w1=__expf(lrelu(a1+aldc)); den1+=w1; acc1+=w1*h1;
    float w2=__expf(lrelu(a2+aldc)); den2+=w2; acc2+=w2*h2;
    float w3=__expf(lrelu(a3+aldc)); den3+=w3; acc3+=w3*h3;
  }
  for(; j<end; j++){
    int s = col[j];
    float w = __expf(lrelu(als[s*8 + hc] + aldc));
    den0 += w;
    acc0 += w * H[s*64 + lane];
  }
  float ws = __expf(lrelu(als[d*8 + hc] + aldc));  // self loop
  float den = ((den0+den1)+(den2+den3)) + ws;
  float acc = ((acc0+acc1)+(acc2+acc3)) + ws * H[d*64 + lane];
  float v = acc / (den + 1e-16f) + b1[lane];
  O[d*64 + lane] = v > 0.f ? v : expm1f(v);        // ELU fused
}

// G = O @ W2 ([64][16]) + layer-2 attention logits (heads=1)
__global__ void k_g(const float* __restrict__ O, const float* __restrict__ W2,
                    const float* __restrict__ asw, const float* __restrict__ adw,
                    float* __restrict__ G, float* __restrict__ as2, float* __restrict__ ad2){
  __shared__ float w2s[64*NCLS];
  for(int i=threadIdx.x; i<64*NCLS; i+=TPB) w2s[i] = W2[i];
  __syncthreads();
  int n = blockIdx.x*TPB + threadIdx.x;
  if(n >= NP) return;
  float g[16];
  #pragma unroll
  for(int c=0;c<16;c++) g[c] = 0.f;
  const float* op = O + n*64;
  #pragma unroll
  for(int k4=0;k4<64;k4+=4){
    float4 v = *(const float4*)(op + k4);
    #pragma unroll
    for(int c=0;c<16;c++){
      g[c] += v.x*w2s[(k4+0)*16+c] + v.y*w2s[(k4+1)*16+c]
            + v.z*w2s[(k4+2)*16+c] + v.w*w2s[(k4+3)*16+c];
    }
  }
  float s=0.f, t=0.f;
  #pragma unroll
  for(int c=0;c<16;c++){ s += g[c]*asw[c]; t += g[c]*adw[c]; }
  #pragma unroll
  for(int c4=0;c4<16;c4+=4)
    *(float4*)(G + n*16 + c4) = make_float4(g[c4],g[c4+1],g[c4+2],g[c4+3]);
  as2[n] = s; ad2[n] = t;
}

// GAT layer-2 gather: one wave per dst, SINGLE-PASS softmax, 2 independent
// chains per lane (slots stride 8: slot and slot+4).
__global__ __launch_bounds__(TPB) void k_agg2(const int* __restrict__ offs,
                                              const int* __restrict__ col,
                                              const float* __restrict__ as2,
                                              const float* __restrict__ ad2,
                                              const float* __restrict__ G,
                                              const float* __restrict__ b2,
                                              float* __restrict__ out){
  int d = (blockIdx.x*TPB + threadIdx.x) >> 6;
  int lane = threadIdx.x & 63;
  int c = lane & 15, slot = lane >> 4;
  int beg = d ? offs[d-1] : 0;
  int end = offs[d];
  float ad2d = ad2[d];
  float den0=0.f, den1=0.f, acc0=0.f, acc1=0.f;
  for(int j0=beg; j0<end; j0+=8){
    int ja = j0 + slot;
    int jb = ja + 4;
    if(ja < end){
      int s = col[ja];
      float w = __expf(lrelu(as2[s] + ad2d));
      den0 += w; acc0 += w * G[s*16 + c];
    }
    if(jb < end){
      int s = col[jb];
      float w = __expf(lrelu(as2[s] + ad2d));
      den1 += w; acc1 += w * G[s*16 + c];
    }
  }
  float acc = acc0 + acc1, den = den0 + den1;
  acc += __shfl_xor(acc, 16);
  acc += __shfl_xor(acc, 32);
  den += __shfl_xor(den, 16);
  den += __shfl_xor(den, 32);
  float ws = __expf(lrelu(as2[d] + ad2d));   // self loop
  den += ws;
  acc += ws * G[d*16 + c];
  if(lane < 16) out[d*16 + c] = acc / (den + 1e-16f) + b2[c];
}

// ===================== launch =====================

extern "C" void kernel_launch(void* const* d_in, const int* in_sizes, int n_in,
                              void* d_out, int out_size, void* d_ws, size_t ws_size,
                              hipStream_t stream){
  const float* x    = (const float*)d_in[0];
  const int*   ei   = (const int*)  d_in[1];
  const float* dx   = (const float*)d_in[2];
  const int*   dei  = (const int*)  d_in[3];
  const float* W1   = (const float*)d_in[4];
  const float* aw1s = (const float*)d_in[5];
  const float* aw1d = (const float*)d_in[6];
  const float* b1   = (const float*)d_in[7];
  const float* W2   = (const float*)d_in[8];
  const float* aw2s = (const float*)d_in[9];
  const float* aw2d = (const float*)d_in[10];
  const float* b2   = (const float*)d_in[11];
  const float* Wg1  = (const float*)d_in[12];
  const float* bg1  = (const float*)d_in[13];
  const float* Wg2  = (const float*)d_in[14];
  const float* bg2  = (const float*)d_in[15];

  float* out = (float*)d_out;          // [NP,16]
  float* Qo  = out + NP*NCLS;          // [NDU,16]

  float* R     = (float*)d_ws;
  float* dinvD = R + 25600000;
  int*   offsD = (int*)(dinvD + 1600000);
  int*   colD  = offsD + 1600000;
  int*   bkt   = colD + 3200000;            // 256 bucket counters

  // dual-phase overlay
  int2*   pairsD = (int2*)R;          // 3.2M int2 (dead after k_csr)
  float4* PX   = (float4*)R;          // 1.6M float4 (after k_csr)
  float*  P2   = R + 6400000;         // 12.8M words
  // primal-phase overlay
  float* H1   = R;                    // 6.4M
  float* O1   = R + 6400000;          // 6.4M
  float* G    = R + 12800000;         // 1.6M
  float* als  = R + 14400000;         // 0.8M
  float* ald  = R + 15200000;         // 0.8M
  float* as2  = R + 16000000;         // 0.1M
  float* ad2  = R + 16100000;         // 0.1M
  float* dinvP= R + 16200000;         // 0.1M (scratch; GAT doesn't use dinv)
  int*   offsP= (int*)(R + 16300000); // 0.1M
  int*   colP = offsP + 100000;       // 1.6M
  int2*  pairsP = (int2*)(R + 19200000); // 1.6M int2 = 3.2M words

  const int* dsrc = dei;
  const int* ddst = dei + EDU;
  const int* esrc = ei;
  const int* edst = ei + EP;

  const int SH_D = 13, NB_D = ((NDU - 1) >> SH_D) + 1;   // 196
  const int SH_P = 9,  NB_P = ((NP  - 1) >> SH_P) + 1;   // 196

  // ---- dual CSR build (bucketed, atomic-free CSR) ----
  hipMemsetAsync(bkt, 0, BKT_MAX*sizeof(int), stream);
  k_bhist<<<(EDU+BCHUNK-1)/BCHUNK, TPB, 0, stream>>>(ddst, bkt, EDU, SH_D);
  k_bscan<<<1, TPB, 0, stream>>>(bkt, NB_D);
  k_bscat<<<(EDU+BCHUNK-1)/BCHUNK, TPB, 0, stream>>>(dsrc, ddst, bkt, pairsD, EDU, SH_D);
  k_csr  <<<NB_D, TPB, (1<<SH_D)*sizeof(int), stream>>>(pairsD, bkt, offsD, dinvD, colD, NDU, SH_D);

  // ---- dual GCN ----
  k_pscale<<<(NDU+TPB-1)/TPB, TPB, 0, stream>>>(dx, dinvD, PX);
  k_dual1 <<<NDU*4/TPB, TPB, 0, stream>>>((const float*)PX, Wg1, bg1, dinvD, offsD, colD, P2);
  k_dual2 <<<NDU*8/TPB, TPB, 0, stream>>>(P2, Wg2, bg2, dinvD, offsD, colD, Qo);

  // ---- primal CSR build (bucketed, atomic-free CSR) ----
  hipMemsetAsync(bkt, 0, BKT_MAX*sizeof(int), stream);
  k_bhist<<<(EP+BCHUNK-1)/BCHUNK, TPB, 0, stream>>>(edst, bkt, EP, SH_P);
  k_bscan<<<1, TPB, 0, stream>>>(bkt, NB_P);
  k_bscat<<<(EP+BCHUNK-1)/BCHUNK, TPB, 0, stream>>>(esrc, edst, bkt, pairsP, EP, SH_P);
  k_csr  <<<NB_P, TPB, (1<<SH_P)*sizeof(int), stream>>>(pairsP, bkt, offsP, dinvP, colP, NP, SH_P);

  // ---- primal GAT ----
  k_gemm1<<<(NP+GBM-1)/GBM, GT, 0, stream>>>(x, W1, H1);
  k_alpha<<<NP*NHEAD/TPB, TPB, 0, stream>>>(H1, aw1s, aw1d, als, ald);
  k_agg1 <<<NP/4, TPB, 0, stream>>>(offsP, colP, als, ald, H1, b1, O1);
  k_g    <<<(NP+TPB-1)/TPB, TPB, 0, stream>>>(O1, W2, aw2s, aw2d, G, as2, ad2);
  k_agg2 <<<NP/4, TPB, 0, stream>>>(offsP, colP, as2, ad2, G, b2, out);
}